// Round 14
// baseline (279.448 us; speedup 1.0000x reference)
//
#include <hip/hip_runtime.h>
#include <hip/hip_bf16.h>
#include <math.h>

#define BB 8
#define CCH 256
#define HWN 4096
#define RR 16

typedef __attribute__((ext_vector_type(8))) short short8;   // 8 bf16 = K=32 MFMA A/B frag (4 VGPRs)
typedef __attribute__((ext_vector_type(4))) float f32x4;    // MFMA C/D frag

static __device__ __forceinline__ unsigned short f2bf(float x) {
    union { float f; unsigned u; } v; v.f = x;
    return (unsigned short)((v.u + 0x8000u) >> 16);   // round-half-up bf16
}

// ---------------- K1: avg+max pool per (b,c); blocks 0..287 also pack Wb (fused wprep) ----
__global__ __launch_bounds__(256) void k_pool(const float* __restrict__ x,
                                              float* __restrict__ avgp,
                                              float* __restrict__ maxp,
                                              const float* __restrict__ vw,
                                              const float* __restrict__ qw,
                                              const float* __restrict__ kw,
                                              unsigned short* __restrict__ Wb) {
    int bc = blockIdx.x;
    int t = threadIdx.x;
    if (bc < 288) {
        int idx = bc * 256 + t;
        int m = idx >> 8, c = idx & 255;
        float v;
        if (m < 256) v = vw[idx];
        else if (m < 272) v = qw[(m - 256) * 256 + c];
        else v = kw[(m - 272) * 256 + c];
        Wb[idx] = f2bf(v);
    }
    const float4* p = (const float4*)(x + (size_t)bc * HWN);
    float s = 0.f, m = -INFINITY;
#pragma unroll
    for (int i = 0; i < 4; ++i) {
        float4 v = p[t + 256 * i];
        s += v.x + v.y + v.z + v.w;
        m = fmaxf(m, fmaxf(fmaxf(v.x, v.y), fmaxf(v.z, v.w)));
    }
    for (int off = 32; off; off >>= 1) {
        s += __shfl_down(s, off);
        m = fmaxf(m, __shfl_down(m, off));
    }
    __shared__ float ss[4], sm[4];
    int wid = t >> 6;
    if ((t & 63) == 0) { ss[wid] = s; sm[wid] = m; }
    __syncthreads();
    if (t == 0) {
        float S = ss[0] + ss[1] + ss[2] + ss[3];
        float M = fmaxf(fmaxf(sm[0], sm[1]), fmaxf(sm[2], sm[3]));
        avgp[bc] = S * (1.f / (float)HWN);
        maxp[bc] = M;
    }
}

// ---------------- K-proj: m-split waves + FUSED SE-GATE prologue (R13, verbatim) --------
__global__ __launch_bounds__(512, 2) void k_proj(const float* __restrict__ x,
                                                 const float* __restrict__ avgp,
                                                 const float* __restrict__ maxp,
                                                 const float* __restrict__ w1,
                                                 const float* __restrict__ w2,
                                                 const unsigned short* __restrict__ Wb,
                                                 const float* __restrict__ vb,
                                                 const float* __restrict__ qb,
                                                 const float* __restrict__ kb,
                                                 float* __restrict__ gate,
                                                 unsigned short* __restrict__ qT,
                                                 unsigned short* __restrict__ kT,
                                                 unsigned short* __restrict__ vB) {
    int b = blockIdx.x & 7;              // XCD swizzle: batch <-> XCD
    int n0 = (blockIdx.x >> 3) << 6;
    int t = threadIdx.x;
    int w = t >> 6, l = t & 63, quad = l >> 4, ln = l & 15;
    int mh = w >> 2;                     // m-half (0: V rows 0-127 + q; 1: V rows 128-255 + k)
    int ws = w & 3;                      // n-slice (0..3) -> n_local = ws*16 + ln

    __shared__ __align__(16) unsigned short xs_t[64][72];    // [n_local][c_local] bf16
    __shared__ __align__(16) unsigned short vtile[256 * 72]; // [m][n_local] bf16, stride 72
    __shared__ float qk_s[32][66];   // q rows 0..15, k rows 16..31 (fp32)
    __shared__ float sa[CCH], sx[CCH], sh[32], gs[CCH];      // fused gate scratch (3.2KB)

    const f32x4 zf = {0.f, 0.f, 0.f, 0.f};
    f32x4 acc[9];                        // [0..7]: V mt = mh*8+mtl; [8]: q (mh=0) / k (mh=1)
#pragma unroll
    for (int a = 0; a < 9; ++a) acc[a] = zf;

    // ---- fused SE gate (redundant per block; ~1us) ----
    if (t < CCH) {
        sa[t] = avgp[b * CCH + t];
        sx[t] = maxp[b * CCH + t];
    }

    // per-it invariant source pointers (cc advances by 64 c-rows = 1<<18 floats)
    const float* xp[2];
#pragma unroll
    for (int it = 0; it < 2; ++it) {
        int idx = it * 512 + t;
        int cl = idx >> 4, nq = idx & 15;
        xp[it] = x + (((size_t)(b * CCH + cl)) << 12) + n0 + nq * 4;
    }
    float4 xr[2];
#pragma unroll
    for (int it = 0; it < 2; ++it) xr[it] = *(const float4*)xp[it];   // prefetch cc=0

    __syncthreads();
    if (t < 32) {
        int r = t & 15;
        const float* src = (t < 16) ? sa : sx;
        float h = 0.f;
        for (int c = 0; c < CCH; ++c) h += w1[r * CCH + c] * src[c];
        sh[t] = fmaxf(h, 0.f);
    }
    __syncthreads();
    if (t < CCH) {
        float g = 0.f;
#pragma unroll
        for (int r = 0; r < RR; ++r) g += w2[t * RR + r] * (sh[r] + sh[16 + r]);
        float gv = 1.f / (1.f + __expf(-g));
        gs[t] = gv;
        if (n0 == 0) gate[b * CCH + t] = gv;   // materialize for k_attn (8 blocks)
    }

    for (int cc = 0; cc < 4; ++cc) {
        __syncthreads();   // xs_t readers from previous cc done (+ gs ready on cc=0)
#pragma unroll
        for (int it = 0; it < 2; ++it) {
            int idx = it * 512 + t;
            int cl = idx >> 4, nq = idx & 15;
            int c = cc * 64 + cl;
            float g = gs[c];
            float4 v = xr[it];
            xs_t[nq * 4 + 0][cl] = f2bf(v.x * g);
            xs_t[nq * 4 + 1][cl] = f2bf(v.y * g);
            xs_t[nq * 4 + 2][cl] = f2bf(v.z * g);
            xs_t[nq * 4 + 3][cl] = f2bf(v.w * g);
        }
        __syncthreads();

        // prefetch next cc's x tile: consumed at next loop top, hidden under MFMA phase
        if (cc < 3) {
#pragma unroll
            for (int it = 0; it < 2; ++it)
                xr[it] = *(const float4*)(xp[it] + (((size_t)(cc + 1)) << 18));
        }

        short8 bfrag[2];
#pragma unroll
        for (int kc = 0; kc < 2; ++kc)
            bfrag[kc] = *(const short8*)&xs_t[ws * 16 + ln][kc * 32 + quad * 8];

#pragma unroll
        for (int mtl = 0; mtl < 8; ++mtl) {
#pragma unroll
            for (int kc = 0; kc < 2; ++kc) {
                short8 af = *(const short8*)(Wb + ((size_t)(mh * 128 + mtl * 16 + ln)) * 256 + cc * 64 + kc * 32 + quad * 8);
                acc[mtl] = __builtin_amdgcn_mfma_f32_16x16x32_bf16(af, bfrag[kc], acc[mtl], 0, 0, 0);
            }
        }
        // q (mh=0: Wb rows 256..271) or k (mh=1: rows 272..287)
#pragma unroll
        for (int kc = 0; kc < 2; ++kc) {
            short8 af = *(const short8*)(Wb + ((size_t)(256 + mh * 16 + ln)) * 256 + cc * 64 + kc * 32 + quad * 8);
            acc[8] = __builtin_amdgcn_mfma_f32_16x16x32_bf16(af, bfrag[kc], acc[8], 0, 0, 0);
        }
    }

    // v rows -> vtile[m][n_local], m = mh*128 + mtl*16 + quad*4 + r, n_local = ws*16+ln
#pragma unroll
    for (int mtl = 0; mtl < 8; ++mtl) {
#pragma unroll
        for (int r = 0; r < 4; ++r) {
            int m = mh * 128 + mtl * 16 + quad * 4 + r;
            vtile[m * 72 + ws * 16 + ln] = f2bf(acc[mtl][r] + vb[m]);
        }
    }
    // q/k -> LDS for transpose: mh=0 waves write q rows 0..15, mh=1 waves k rows 16..31
#pragma unroll
    for (int r = 0; r < 4; ++r)
        qk_s[mh * 16 + quad * 4 + r][ws * 16 + ln] = acc[8][r];
    __syncthreads();

    // stream vtile -> vB chunks: 512 thr: c = t&255, 4 x 16B stores, coalesced segments
    {
        unsigned short* vBp = vB + (((size_t)b) << 20);
        int c = t & 255, Qh = (t >> 8) * 4;
#pragma unroll
        for (int qq = 0; qq < 4; ++qq) {
            int Q = Qh + qq;
            short8 v8 = *(const short8*)(vtile + c * 72 + Q * 8);
            *(short8*)(vBp + ((size_t)((((n0 >> 3) + Q) << 8) + c) << 3)) = v8;
        }
    }
    if (t < 128) {
        int isK = t >> 6;
        int n = t & 63;
        const float* bias = isK ? kb : qb;
        unsigned u32[8];
#pragma unroll
        for (int j = 0; j < 8; ++j) {
            unsigned lo = f2bf(qk_s[isK * 16 + 2 * j][n] + bias[2 * j]);
            unsigned hi = f2bf(qk_s[isK * 16 + 2 * j + 1][n] + bias[2 * j + 1]);
            u32[j] = lo | (hi << 16);
        }
        unsigned short* dst = (isK ? kT : qT) + ((size_t)(b * HWN + n0 + n)) * RR;
        uint4 d0 = {u32[0], u32[1], u32[2], u32[3]};
        uint4 d1 = {u32[4], u32[5], u32[6], u32[7]};
        ((uint4*)dst)[0] = d0;
        ((uint4*)dst)[1] = d1;
    }
}

// ---------------- K-attn: (32c x 64i) waves, 4-WAVE BLOCKS, grid 1024 = 4 blocks/CU -----
// R13 post-mortem: k_attn at 93 with grid 512 = 2 blocks/CU = 2 barrier domains; far from
// HW roofline (MFMA 36%, HBM 8.5%) -> overlap-limited. THIS ROUND: same wave geometry
// (traffic-optimal (32c,64i), acc[2][4]), but block = 4 waves covering (128c x 64i) via
// c-half bit ch; grid 1024 -> 4 blocks/CU = 4 independent barrier domains, same per-CU
// traffic (V-L2: 1024x1MB == 512x2MB; P-LDS: same 16 waves/CU; K-loads LESS redundant:
// 1 wave per jsub, was 2). Each wave: jsub = w, produces ALL 4 i-subtiles (bq[4], 4 QK
// MFMA + 16 exp per chunk); PV identical to champion. LDS/block unchanged 34KB (4x34=136
// <160). VGPR ~116 under (256,4) cap 128 (16 waves/CU rule). Adjacent ch-pair blocks
// share Q/K in L2 (same i0).
__global__ __launch_bounds__(256, 4) void k_attn(const unsigned short* __restrict__ qT,
                                                 const unsigned short* __restrict__ kT,
                                                 const unsigned short* __restrict__ vB,
                                                 const float* __restrict__ x,
                                                 const float* __restrict__ gate,
                                                 const float* __restrict__ gamma,
                                                 float* __restrict__ out) {
    int b = blockIdx.x & 7;
    int ch = (blockIdx.x >> 3) & 1;      // c-half (0: c 0-127, 1: c 128-255)
    int i0 = (blockIdx.x >> 4) << 6;     // 64-i tile
    int t = threadIdx.x;
    int w = __builtin_amdgcn_readfirstlane(t >> 6);   // wave-uniform -> SGPR
    int l = t & 63;
    int quad = l >> 4, ln = l & 15;
    int jsub = w;                        // S-production j-tile (0..3), unique per wave
    int c0 = ch * 128 + w * 32;          // PV c-range: exclusive per wave

    __shared__ __align__(16) unsigned short p_lds[4][4096];   // 4 bufs, chunk-major, 8KB each
    __shared__ float l_s[4][68];

    const short8 zs = {0, 0, 0, 0, 0, 0, 0, 0};
    const f32x4 zf = {0.f, 0.f, 0.f, 0.f};

    // four persistent Q B-frags: B[k=d=quad*8+kk][n=i], i = i0 + u*16 + ln (u=0..3)
    short8 bq[4];
#pragma unroll
    for (int u = 0; u < 4; ++u) bq[u] = zs;
    if (quad < 2) {
#pragma unroll
        for (int u = 0; u < 4; ++u)
            bq[u] = *(const short8*)(qT + (((size_t)(b * HWN + i0 + u * 16 + ln)) << 4) + (quad << 3));
    }

    f32x4 acc[2][4];   // [cs][is]: c = c0+cs*16+quad*4+r, i = is*16+ln
#pragma unroll
    for (int cs = 0; cs < 2; ++cs)
#pragma unroll
        for (int is = 0; is < 4; ++is) acc[cs][is] = zf;
    float lsum[4] = {0.f, 0.f, 0.f, 0.f};

    const float c1 = 1.44269504f;      // log2(e)
    const float c0e = -11.5415603f;    // -8*log2(e): fixed shift, cancels in p/l

    // uniform (SGPR) bases + loop-invariant per-lane (VGPR) offsets, ushort units
    const unsigned short* kb_u = kT + ((size_t)(b * HWN)) * RR;
    const int kln = ((jsub * 16 + ln) << 4) + (quad << 3);
    const unsigned short* vb_u = vB + (((size_t)b) << 20) + ((size_t)c0 << 3);
    int vln[4];
#pragma unroll
    for (int ks = 0; ks < 2; ++ks)
#pragma unroll
        for (int cs = 0; cs < 2; ++cs)
            vln[ks * 2 + cs] = (((ks * 4 + quad) << 8) + cs * 16 + ln) << 3;

    // P LDS offsets (ushort units), layout offset(i,j) = ((j>>3)*64 + i)*8 + (j&7)
    // store: j = jsub*16 + quad*4 + r, i = u*16 + ln  -> soff + u*128
    int soff = ((jsub * 2 + (quad >> 1)) * 64 + ln) * 8 + (quad & 1) * 4;
    // read: jc = ks*4 + quad, i = is*16 + ln  -> rbase + ks*2048 + is*128
    int rbase = quad * 512 + ln * 8;

    short8 akA = zs, akB = zs;          // K A-frags: chunk0 / chunk1 of current superstep
    short8 avA[4], avB[4];              // V A-frags: chunk0 / chunk1, [ks*2+cs]

    auto load_ak = [&](short8& ak, int j0) {
        if (quad < 2) ak = *(const short8*)(kb_u + ((j0 << 4) + kln));
    };
    auto load_av = [&](short8 (&av)[4], int j0) {
        const unsigned short* vp = vb_u + (j0 << 8);   // scalar advance
#pragma unroll
        for (int u = 0; u < 4; ++u) av[u] = *(const short8*)(vp + vln[u]);
    };

    load_ak(akA, 0);
    load_ak(akB, 64);
    load_av(avA, 0);
    load_av(avB, 64);

    // exp + pack + store one S^T tile (chunk pbuf, i-subtile u)
    auto finish_s = [&](const f32x4& sf, unsigned short* pbuf, int u) {
        float p0 = exp2f(fmaf(sf[0], c1, c0e));
        float p1 = exp2f(fmaf(sf[1], c1, c0e));
        float p2 = exp2f(fmaf(sf[2], c1, c0e));
        float p3 = exp2f(fmaf(sf[3], c1, c0e));
        lsum[u] += (p0 + p1) + (p2 + p3);
        uint2 pk;
        asm("v_cvt_pk_bf16_f32 %0, %1, %2" : "=v"(pk.x) : "v"(p0), "v"(p1));
        asm("v_cvt_pk_bf16_f32 %0, %1, %2" : "=v"(pk.y) : "v"(p2), "v"(p3));
        *(uint2*)(pbuf + soff + u * 128) = pk;
    };

    // PV over one 64-j chunk: 8 b128 P reads + 16 MFMAs (c 32 x i 64)
    auto pv = [&](const short8 (&av)[4], const unsigned short* pbuf) {
#pragma unroll
        for (int ks = 0; ks < 2; ++ks) {
            short8 bp[4];
#pragma unroll
            for (int is = 0; is < 4; ++is)
                bp[is] = *(const short8*)(pbuf + rbase + ks * 2048 + is * 128);
#pragma unroll
            for (int cs = 0; cs < 2; ++cs)
#pragma unroll
                for (int is = 0; is < 4; ++is)
                    acc[cs][is] = __builtin_amdgcn_mfma_f32_16x16x32_bf16(av[ks * 2 + cs], bp[is], acc[cs][is], 0, 0, 0);
        }
    };

    for (int jt = 0; jt < 32; ++jt) {
        unsigned short* pb0 = &p_lds[(jt & 1) * 2 + 0][0];
        unsigned short* pb1 = &p_lds[(jt & 1) * 2 + 1][0];

        // ---- QK both chunks x 4 i-subtiles (consumes akA/akB), P stores ----
        f32x4 sA[4], sB[4];
#pragma unroll
        for (int u = 0; u < 4; ++u)
            sA[u] = __builtin_amdgcn_mfma_f32_16x16x32_bf16(akA, bq[u], zf, 0, 0, 0);
#pragma unroll
        for (int u = 0; u < 4; ++u)
            sB[u] = __builtin_amdgcn_mfma_f32_16x16x32_bf16(akB, bq[u], zf, 0, 0, 0);
#pragma unroll
        for (int u = 0; u < 4; ++u) finish_s(sA[u], pb0, u);
#pragma unroll
        for (int u = 0; u < 4; ++u) finish_s(sB[u], pb1, u);

        __syncthreads();   // ONE barrier per 128 j: P pair visible; prev prefetches drained

        bool pf = jt < 31;
        int j0n = (jt + 1) << 7;
        // K prefetch for next superstep (akA/akB free after QK above)
        if (pf) { load_ak(akA, j0n); load_ak(akB, j0n + 64); }

        // PV chunk0 (consumes avA) then refill avA; PV chunk1 then refill avB
        pv(avA, pb0);
        if (pf) load_av(avA, j0n);
        pv(avB, pb1);
        if (pf) load_av(avB, j0n + 64);
    }

    // l reduction: lane's lsum[u] covers its 4 j's (tile jsub) at i = u*16 + ln
#pragma unroll
    for (int u = 0; u < 4; ++u) {
        lsum[u] += __shfl_xor(lsum[u], 16, 64);
        lsum[u] += __shfl_xor(lsum[u], 32, 64);
    }
    if (l < 16) {
#pragma unroll
        for (int u = 0; u < 4; ++u)
            l_s[jsub][u * 16 + l] = lsum[u];
    }
    __syncthreads();

    float g = gamma[0];
    float rinv[4];
#pragma unroll
    for (int is = 0; is < 4; ++is) {
        int i = is * 16 + ln;
        float lf = (l_s[0][i] + l_s[1][i]) + (l_s[2][i] + l_s[3][i]);
        rinv[is] = g / lf;
    }

    // epilogue: out = gamma*o/l + x*gate
#pragma unroll
    for (int cs = 0; cs < 2; ++cs) {
#pragma unroll
        for (int r = 0; r < 4; ++r) {
            int c = c0 + cs * 16 + quad * 4 + r;
            float gc = gate[b * CCH + c];
            size_t rowoff = (((size_t)(b * CCH + c)) << 12) + i0;
            float* po = out + rowoff;
            const float* px = x + rowoff;
#pragma unroll
            for (int is = 0; is < 4; ++is) {
                int idx = is * 16 + ln;
                po[idx] = acc[cs][is][r] * rinv[is] + px[idx] * gc;
            }
        }
    }
}

extern "C" void kernel_launch(void* const* d_in, const int* in_sizes, int n_in,
                              void* d_out, int out_size, void* d_ws, size_t ws_size,
                              hipStream_t stream) {
    const float* x = (const float*)d_in[0];
    const float* w1 = (const float*)d_in[1];
    const float* w2 = (const float*)d_in[2];
    const float* qw = (const float*)d_in[3];
    const float* qb = (const float*)d_in[4];
    const float* kw = (const float*)d_in[5];
    const float* kb = (const float*)d_in[6];
    const float* vw = (const float*)d_in[7];
    const float* vb = (const float*)d_in[8];
    const float* gamma = (const float*)d_in[9];
    float* out = (float*)d_out;
    char* ws = (char*)d_ws;

    float* avgp = (float*)(ws);                        // 8 KB
    float* maxp = (float*)(ws + 8192);                 // 8 KB
    float* gate = (float*)(ws + 16384);                // 8 KB
    unsigned short* Wb = (unsigned short*)(ws + 24576);               // [288][256] bf16
    unsigned short* qT = (unsigned short*)(ws + 24576 + 147456);      // 1 MB [b][n][16]
    unsigned short* kT = (unsigned short*)(ws + 24576 + 147456 + 1048576);
    unsigned short* vB = (unsigned short*)(ws + 24576 + 147456 + 2097152);  // 16.8 MB chunked

    k_pool<<<2048, 256, 0, stream>>>(x, avgp, maxp, vw, qw, kw, Wb);  // + fused wprep
    k_proj<<<512, 512, 0, stream>>>(x, avgp, maxp, w1, w2, Wb, vb, qb, kb, gate, qT, kT, vB);
    k_attn<<<1024, 256, 0, stream>>>(qT, kT, vB, x, gate, gamma, out);
}

// Round 15
// 220.864 us; speedup vs baseline: 1.2653x; 1.2653x over previous
//
#include <hip/hip_runtime.h>
#include <hip/hip_bf16.h>
#include <math.h>

#define BB 8
#define CCH 256
#define HWN 4096
#define RR 16

typedef __attribute__((ext_vector_type(8))) short short8;   // 8 bf16 = K=32 MFMA A/B frag (4 VGPRs)
typedef __attribute__((ext_vector_type(4))) float f32x4;    // MFMA C/D frag

static __device__ __forceinline__ unsigned short f2bf(float x) {
    union { float f; unsigned u; } v; v.f = x;
    return (unsigned short)((v.u + 0x8000u) >> 16);   // round-half-up bf16
}

// ---------------- K1: avg+max pool per (b,c); blocks 0..287 also pack Wb (fused wprep) ----
__global__ __launch_bounds__(256) void k_pool(const float* __restrict__ x,
                                              float* __restrict__ avgp,
                                              float* __restrict__ maxp,
                                              const float* __restrict__ vw,
                                              const float* __restrict__ qw,
                                              const float* __restrict__ kw,
                                              unsigned short* __restrict__ Wb) {
    int bc = blockIdx.x;
    int t = threadIdx.x;
    if (bc < 288) {
        int idx = bc * 256 + t;
        int m = idx >> 8, c = idx & 255;
        float v;
        if (m < 256) v = vw[idx];
        else if (m < 272) v = qw[(m - 256) * 256 + c];
        else v = kw[(m - 272) * 256 + c];
        Wb[idx] = f2bf(v);
    }
    const float4* p = (const float4*)(x + (size_t)bc * HWN);
    float s = 0.f, m = -INFINITY;
#pragma unroll
    for (int i = 0; i < 4; ++i) {
        float4 v = p[t + 256 * i];
        s += v.x + v.y + v.z + v.w;
        m = fmaxf(m, fmaxf(fmaxf(v.x, v.y), fmaxf(v.z, v.w)));
    }
    for (int off = 32; off; off >>= 1) {
        s += __shfl_down(s, off);
        m = fmaxf(m, __shfl_down(m, off));
    }
    __shared__ float ss[4], sm[4];
    int wid = t >> 6;
    if ((t & 63) == 0) { ss[wid] = s; sm[wid] = m; }
    __syncthreads();
    if (t == 0) {
        float S = ss[0] + ss[1] + ss[2] + ss[3];
        float M = fmaxf(fmaxf(sm[0], sm[1]), fmaxf(sm[2], sm[3]));
        avgp[bc] = S * (1.f / (float)HWN);
        maxp[bc] = M;
    }
}

// ---------------- K-proj: m-split waves + FUSED SE-GATE prologue (R13 champion) ---------
// R14 post-mortem: (256,4) launch-bounds capped VGPR at 64 (NOT the predicted 128) ->
// third spill incident; launch-bounds register caps are only trustworthy at measured
// configs: (512,4)->64, (512,2)->128. Reverted to R13 champion (222.59us total).
__global__ __launch_bounds__(512, 2) void k_proj(const float* __restrict__ x,
                                                 const float* __restrict__ avgp,
                                                 const float* __restrict__ maxp,
                                                 const float* __restrict__ w1,
                                                 const float* __restrict__ w2,
                                                 const unsigned short* __restrict__ Wb,
                                                 const float* __restrict__ vb,
                                                 const float* __restrict__ qb,
                                                 const float* __restrict__ kb,
                                                 float* __restrict__ gate,
                                                 unsigned short* __restrict__ qT,
                                                 unsigned short* __restrict__ kT,
                                                 unsigned short* __restrict__ vB) {
    int b = blockIdx.x & 7;              // XCD swizzle: batch <-> XCD
    int n0 = (blockIdx.x >> 3) << 6;
    int t = threadIdx.x;
    int w = t >> 6, l = t & 63, quad = l >> 4, ln = l & 15;
    int mh = w >> 2;                     // m-half (0: V rows 0-127 + q; 1: V rows 128-255 + k)
    int ws = w & 3;                      // n-slice (0..3) -> n_local = ws*16 + ln

    __shared__ __align__(16) unsigned short xs_t[64][72];    // [n_local][c_local] bf16
    __shared__ __align__(16) unsigned short vtile[256 * 72]; // [m][n_local] bf16, stride 72
    __shared__ float qk_s[32][66];   // q rows 0..15, k rows 16..31 (fp32)
    __shared__ float sa[CCH], sx[CCH], sh[32], gs[CCH];      // fused gate scratch (3.2KB)

    const f32x4 zf = {0.f, 0.f, 0.f, 0.f};
    f32x4 acc[9];                        // [0..7]: V mt = mh*8+mtl; [8]: q (mh=0) / k (mh=1)
#pragma unroll
    for (int a = 0; a < 9; ++a) acc[a] = zf;

    // ---- fused SE gate (redundant per block; ~1us) ----
    if (t < CCH) {
        sa[t] = avgp[b * CCH + t];
        sx[t] = maxp[b * CCH + t];
    }

    // per-it invariant source pointers (cc advances by 64 c-rows = 1<<18 floats)
    const float* xp[2];
#pragma unroll
    for (int it = 0; it < 2; ++it) {
        int idx = it * 512 + t;
        int cl = idx >> 4, nq = idx & 15;
        xp[it] = x + (((size_t)(b * CCH + cl)) << 12) + n0 + nq * 4;
    }
    float4 xr[2];
#pragma unroll
    for (int it = 0; it < 2; ++it) xr[it] = *(const float4*)xp[it];   // prefetch cc=0

    __syncthreads();
    if (t < 32) {
        int r = t & 15;
        const float* src = (t < 16) ? sa : sx;
        float h = 0.f;
        for (int c = 0; c < CCH; ++c) h += w1[r * CCH + c] * src[c];
        sh[t] = fmaxf(h, 0.f);
    }
    __syncthreads();
    if (t < CCH) {
        float g = 0.f;
#pragma unroll
        for (int r = 0; r < RR; ++r) g += w2[t * RR + r] * (sh[r] + sh[16 + r]);
        float gv = 1.f / (1.f + __expf(-g));
        gs[t] = gv;
        if (n0 == 0) gate[b * CCH + t] = gv;   // materialize for k_attn (8 blocks)
    }

    for (int cc = 0; cc < 4; ++cc) {
        __syncthreads();   // xs_t readers from previous cc done (+ gs ready on cc=0)
#pragma unroll
        for (int it = 0; it < 2; ++it) {
            int idx = it * 512 + t;
            int cl = idx >> 4, nq = idx & 15;
            int c = cc * 64 + cl;
            float g = gs[c];
            float4 v = xr[it];
            xs_t[nq * 4 + 0][cl] = f2bf(v.x * g);
            xs_t[nq * 4 + 1][cl] = f2bf(v.y * g);
            xs_t[nq * 4 + 2][cl] = f2bf(v.z * g);
            xs_t[nq * 4 + 3][cl] = f2bf(v.w * g);
        }
        __syncthreads();

        // prefetch next cc's x tile: consumed at next loop top, hidden under MFMA phase
        if (cc < 3) {
#pragma unroll
            for (int it = 0; it < 2; ++it)
                xr[it] = *(const float4*)(xp[it] + (((size_t)(cc + 1)) << 18));
        }

        short8 bfrag[2];
#pragma unroll
        for (int kc = 0; kc < 2; ++kc)
            bfrag[kc] = *(const short8*)&xs_t[ws * 16 + ln][kc * 32 + quad * 8];

#pragma unroll
        for (int mtl = 0; mtl < 8; ++mtl) {
#pragma unroll
            for (int kc = 0; kc < 2; ++kc) {
                short8 af = *(const short8*)(Wb + ((size_t)(mh * 128 + mtl * 16 + ln)) * 256 + cc * 64 + kc * 32 + quad * 8);
                acc[mtl] = __builtin_amdgcn_mfma_f32_16x16x32_bf16(af, bfrag[kc], acc[mtl], 0, 0, 0);
            }
        }
        // q (mh=0: Wb rows 256..271) or k (mh=1: rows 272..287)
#pragma unroll
        for (int kc = 0; kc < 2; ++kc) {
            short8 af = *(const short8*)(Wb + ((size_t)(256 + mh * 16 + ln)) * 256 + cc * 64 + kc * 32 + quad * 8);
            acc[8] = __builtin_amdgcn_mfma_f32_16x16x32_bf16(af, bfrag[kc], acc[8], 0, 0, 0);
        }
    }

    // v rows -> vtile[m][n_local], m = mh*128 + mtl*16 + quad*4 + r, n_local = ws*16+ln
#pragma unroll
    for (int mtl = 0; mtl < 8; ++mtl) {
#pragma unroll
        for (int r = 0; r < 4; ++r) {
            int m = mh * 128 + mtl * 16 + quad * 4 + r;
            vtile[m * 72 + ws * 16 + ln] = f2bf(acc[mtl][r] + vb[m]);
        }
    }
    // q/k -> LDS for transpose: mh=0 waves write q rows 0..15, mh=1 waves k rows 16..31
#pragma unroll
    for (int r = 0; r < 4; ++r)
        qk_s[mh * 16 + quad * 4 + r][ws * 16 + ln] = acc[8][r];
    __syncthreads();

    // stream vtile -> vB chunks: 512 thr: c = t&255, 4 x 16B stores, coalesced segments
    {
        unsigned short* vBp = vB + (((size_t)b) << 20);
        int c = t & 255, Qh = (t >> 8) * 4;
#pragma unroll
        for (int qq = 0; qq < 4; ++qq) {
            int Q = Qh + qq;
            short8 v8 = *(const short8*)(vtile + c * 72 + Q * 8);
            *(short8*)(vBp + ((size_t)((((n0 >> 3) + Q) << 8) + c) << 3)) = v8;
        }
    }
    if (t < 128) {
        int isK = t >> 6;
        int n = t & 63;
        const float* bias = isK ? kb : qb;
        unsigned u32[8];
#pragma unroll
        for (int j = 0; j < 8; ++j) {
            unsigned lo = f2bf(qk_s[isK * 16 + 2 * j][n] + bias[2 * j]);
            unsigned hi = f2bf(qk_s[isK * 16 + 2 * j + 1][n] + bias[2 * j + 1]);
            u32[j] = lo | (hi << 16);
        }
        unsigned short* dst = (isK ? kT : qT) + ((size_t)(b * HWN + n0 + n)) * RR;
        uint4 d0 = {u32[0], u32[1], u32[2], u32[3]};
        uint4 d1 = {u32[4], u32[5], u32[6], u32[7]};
        ((uint4*)dst)[0] = d0;
        ((uint4*)dst)[1] = d1;
    }
}

// ---------------- K-attn: TRUE R3 champion — verbatim (91.6-94.5us measured) ------------
// (32c x 64i) waves: acc[2][4] = 32 f32; wave w: PV c-range c0 = w*32 (exclusive),
// PV i-range FULL 64 (is 0..3); S production jsub = w>>1 (j-tile), ih = w&1 (i-half).
// Grid 512, 1 barrier per 128j superstep, V/K register dbuf refilled per superstep.
// R14 post-mortem: 4-wave/4-domain variant spilled under the (256,4) 64-reg cap and
// doubled bank conflicts -> 163us. This (512,4)/64-reg shape is the measured optimum.
__global__ __launch_bounds__(512, 4) void k_attn(const unsigned short* __restrict__ qT,
                                                 const unsigned short* __restrict__ kT,
                                                 const unsigned short* __restrict__ vB,
                                                 const float* __restrict__ x,
                                                 const float* __restrict__ gate,
                                                 const float* __restrict__ gamma,
                                                 float* __restrict__ out) {
    int b = blockIdx.x & 7;
    int i0 = (blockIdx.x >> 3) << 6;     // 64-i tile
    int t = threadIdx.x;
    int w = __builtin_amdgcn_readfirstlane(t >> 6);   // wave-uniform -> SGPR
    int l = t & 63;
    int quad = l >> 4, ln = l & 15;
    int jsub = w >> 1;                   // S-production j-tile (0..3)
    int ih = w & 1;                      // S-production i-half (0..1)
    int c0 = w * 32;                     // PV c-range: exclusive per wave

    __shared__ __align__(16) unsigned short p_lds[4][4096];   // 4 bufs, chunk-major, 8KB each
    __shared__ float l_s[4][68];

    const short8 zs = {0, 0, 0, 0, 0, 0, 0, 0};
    const f32x4 zf = {0.f, 0.f, 0.f, 0.f};

    // two persistent Q B-frags: B[k=d=quad*8+kk][n=i], i = i0 + ih*32 + u*16 + ln
    short8 bq[2];
    bq[0] = zs; bq[1] = zs;
    if (quad < 2) {
#pragma unroll
        for (int u = 0; u < 2; ++u)
            bq[u] = *(const short8*)(qT + (((size_t)(b * HWN + i0 + ih * 32 + u * 16 + ln)) << 4) + (quad << 3));
    }

    f32x4 acc[2][4];   // [cs][is]: c = c0+cs*16+quad*4+r, i = is*16+ln
#pragma unroll
    for (int cs = 0; cs < 2; ++cs)
#pragma unroll
        for (int is = 0; is < 4; ++is) acc[cs][is] = zf;
    float lsum[2] = {0.f, 0.f};

    const float c1 = 1.44269504f;      // log2(e)
    const float c0e = -11.5415603f;    // -8*log2(e): fixed shift, cancels in p/l

    // uniform (SGPR) bases + loop-invariant per-lane (VGPR) offsets, ushort units
    const unsigned short* kb_u = kT + ((size_t)(b * HWN)) * RR;
    const int kln = ((jsub * 16 + ln) << 4) + (quad << 3);
    const unsigned short* vb_u = vB + (((size_t)b) << 20) + ((size_t)c0 << 3);
    int vln[4];
#pragma unroll
    for (int ks = 0; ks < 2; ++ks)
#pragma unroll
        for (int cs = 0; cs < 2; ++cs)
            vln[ks * 2 + cs] = (((ks * 4 + quad) << 8) + cs * 16 + ln) << 3;

    // P LDS offsets (ushort units), layout offset(i,j) = ((j>>3)*64 + i)*8 + (j&7)
    // store: j = jsub*16 + quad*4 + r, i = ih*32 + u*16 + ln  -> soff + u*128
    int soff = ((jsub * 2 + (quad >> 1)) * 64 + ih * 32 + ln) * 8 + (quad & 1) * 4;
    // read: jc = ks*4 + quad, i = is*16 + ln  -> rbase + ks*2048 + is*128
    int rbase = quad * 512 + ln * 8;

    short8 akA = zs, akB = zs;          // K A-frags: chunk0 / chunk1 of current superstep
    short8 avA[4], avB[4];              // V A-frags: chunk0 / chunk1, [ks*2+cs]

    auto load_ak = [&](short8& ak, int j0) {
        if (quad < 2) ak = *(const short8*)(kb_u + ((j0 << 4) + kln));
    };
    auto load_av = [&](short8 (&av)[4], int j0) {
        const unsigned short* vp = vb_u + (j0 << 8);   // scalar advance
#pragma unroll
        for (int u = 0; u < 4; ++u) av[u] = *(const short8*)(vp + vln[u]);
    };

    load_ak(akA, 0);
    load_ak(akB, 64);
    load_av(avA, 0);
    load_av(avB, 64);

    // exp + pack + store one S^T tile (chunk pbuf, i-subtile u)
    auto finish_s = [&](const f32x4& sf, unsigned short* pbuf, int u) {
        float p0 = exp2f(fmaf(sf[0], c1, c0e));
        float p1 = exp2f(fmaf(sf[1], c1, c0e));
        float p2 = exp2f(fmaf(sf[2], c1, c0e));
        float p3 = exp2f(fmaf(sf[3], c1, c0e));
        lsum[u] += (p0 + p1) + (p2 + p3);
        uint2 pk;
        asm("v_cvt_pk_bf16_f32 %0, %1, %2" : "=v"(pk.x) : "v"(p0), "v"(p1));
        asm("v_cvt_pk_bf16_f32 %0, %1, %2" : "=v"(pk.y) : "v"(p2), "v"(p3));
        *(uint2*)(pbuf + soff + u * 128) = pk;
    };

    // PV over one 64-j chunk: 8 b128 P reads + 16 MFMAs (c 32 x i 64)
    auto pv = [&](const short8 (&av)[4], const unsigned short* pbuf) {
#pragma unroll
        for (int ks = 0; ks < 2; ++ks) {
            short8 bp[4];
#pragma unroll
            for (int is = 0; is < 4; ++is)
                bp[is] = *(const short8*)(pbuf + rbase + ks * 2048 + is * 128);
#pragma unroll
            for (int cs = 0; cs < 2; ++cs)
#pragma unroll
                for (int is = 0; is < 4; ++is)
                    acc[cs][is] = __builtin_amdgcn_mfma_f32_16x16x32_bf16(av[ks * 2 + cs], bp[is], acc[cs][is], 0, 0, 0);
        }
    };

    for (int jt = 0; jt < 32; ++jt) {
        unsigned short* pb0 = &p_lds[(jt & 1) * 2 + 0][0];
        unsigned short* pb1 = &p_lds[(jt & 1) * 2 + 1][0];

        // ---- QK both chunks x both i-subtiles (consumes akA/akB), P stores ----
        f32x4 sf00 = __builtin_amdgcn_mfma_f32_16x16x32_bf16(akA, bq[0], zf, 0, 0, 0);
        f32x4 sf01 = __builtin_amdgcn_mfma_f32_16x16x32_bf16(akA, bq[1], zf, 0, 0, 0);
        f32x4 sf10 = __builtin_amdgcn_mfma_f32_16x16x32_bf16(akB, bq[0], zf, 0, 0, 0);
        f32x4 sf11 = __builtin_amdgcn_mfma_f32_16x16x32_bf16(akB, bq[1], zf, 0, 0, 0);
        finish_s(sf00, pb0, 0);
        finish_s(sf01, pb0, 1);
        finish_s(sf10, pb1, 0);
        finish_s(sf11, pb1, 1);

        __syncthreads();   // ONE barrier per 128 j: P pair visible; prev prefetches drained

        bool pf = jt < 31;
        int j0n = (jt + 1) << 7;
        // K prefetch for next superstep (akA/akB free after QK above)
        if (pf) { load_ak(akA, j0n); load_ak(akB, j0n + 64); }

        // PV chunk0 (consumes avA) then refill avA; PV chunk1 then refill avB
        pv(avA, pb0);
        if (pf) load_av(avA, j0n);
        pv(avB, pb1);
        if (pf) load_av(avB, j0n + 64);
    }

    // l reduction: lane's lsum[u] covers its 4 j's for i = ih*32 + u*16 + ln
    lsum[0] += __shfl_xor(lsum[0], 16, 64);
    lsum[0] += __shfl_xor(lsum[0], 32, 64);
    lsum[1] += __shfl_xor(lsum[1], 16, 64);
    lsum[1] += __shfl_xor(lsum[1], 32, 64);
    if (l < 16) {
        l_s[jsub][ih * 32 + l] = lsum[0];
        l_s[jsub][ih * 32 + 16 + l] = lsum[1];
    }
    __syncthreads();

    float g = gamma[0];
    float rinv[4];
#pragma unroll
    for (int is = 0; is < 4; ++is) {
        int i = is * 16 + ln;
        float lf = (l_s[0][i] + l_s[1][i]) + (l_s[2][i] + l_s[3][i]);
        rinv[is] = g / lf;
    }

    // epilogue: out = gamma*o/l + x*gate
#pragma unroll
    for (int cs = 0; cs < 2; ++cs) {
#pragma unroll
        for (int r = 0; r < 4; ++r) {
            int c = c0 + cs * 16 + quad * 4 + r;
            float gc = gate[b * CCH + c];
            size_t rowoff = (((size_t)(b * CCH + c)) << 12) + i0;
            float* po = out + rowoff;
            const float* px = x + rowoff;
#pragma unroll
            for (int is = 0; is < 4; ++is) {
                int idx = is * 16 + ln;
                po[idx] = acc[cs][is][r] * rinv[is] + px[idx] * gc;
            }
        }
    }
}

extern "C" void kernel_launch(void* const* d_in, const int* in_sizes, int n_in,
                              void* d_out, int out_size, void* d_ws, size_t ws_size,
                              hipStream_t stream) {
    const float* x = (const float*)d_in[0];
    const float* w1 = (const float*)d_in[1];
    const float* w2 = (const float*)d_in[2];
    const float* qw = (const float*)d_in[3];
    const float* qb = (const float*)d_in[4];
    const float* kw = (const float*)d_in[5];
    const float* kb = (const float*)d_in[6];
    const float* vw = (const float*)d_in[7];
    const float* vb = (const float*)d_in[8];
    const float* gamma = (const float*)d_in[9];
    float* out = (float*)d_out;
    char* ws = (char*)d_ws;

    float* avgp = (float*)(ws);                        // 8 KB
    float* maxp = (float*)(ws + 8192);                 // 8 KB
    float* gate = (float*)(ws + 16384);                // 8 KB
    unsigned short* Wb = (unsigned short*)(ws + 24576);               // [288][256] bf16
    unsigned short* qT = (unsigned short*)(ws + 24576 + 147456);      // 1 MB [b][n][16]
    unsigned short* kT = (unsigned short*)(ws + 24576 + 147456 + 1048576);
    unsigned short* vB = (unsigned short*)(ws + 24576 + 147456 + 2097152);  // 16.8 MB chunked

    k_pool<<<2048, 256, 0, stream>>>(x, avgp, maxp, vw, qw, kw, Wb);  // + fused wprep
    k_proj<<<512, 512, 0, stream>>>(x, avgp, maxp, w1, w2, Wb, vb, qb, kb, gate, qT, kT, vB);
    k_attn<<<512, 512, 0, stream>>>(qT, kT, vB, x, gate, gamma, out);
}